// Round 6
// baseline (304.125 us; speedup 1.0000x reference)
//
#include <hip/hip_runtime.h>
#include <cstdint>
#include <cstddef>

#define N_NODES 12288
#define B_EX    64
#define R_REG   36
#define E_EDGES 196608
#define DD_IN   512
#define DD_OUT  512
#define P_DIM   256
#define D_IMG   1024
#define TANH_C  2.885390081777927f   // 2*log2(e)

// A2 concatenated GEMM operand: [12288][2048] bf16
#define A2_LD     2048
#define IMG_OFF   0
#define NEIGH_OFF 1024
#define H1_OFF    1536

typedef unsigned short ushort;
typedef __bf16 bf16x8 __attribute__((ext_vector_type(8)));
typedef float f32x4 __attribute__((ext_vector_type(4)));
typedef ushort ushort4v __attribute__((ext_vector_type(4)));
typedef ushort ushort8v __attribute__((ext_vector_type(8)));

__device__ __forceinline__ ushort f2bf(float f) {
    uint32_t u = __float_as_uint(f);
    uint32_t r = (u + 0x7fffu + ((u >> 16) & 1u)) >> 16;
    return (ushort)r;
}
__device__ __forceinline__ float bf2f(ushort u) {
    return __uint_as_float(((uint32_t)u) << 16);
}
__device__ __forceinline__ void gload_lds16(const void* g, void* l) {
    __builtin_amdgcn_global_load_lds((const __attribute__((address_space(1))) void*)g,
                                     (__attribute__((address_space(3))) void*)l, 16, 0, 0);
}
__device__ __forceinline__ float fexp2(float x) {
    float r; asm("v_exp_f32 %0, %1" : "=v"(r) : "v"(x)); return r;
}
__device__ __forceinline__ float frcp(float x) {
    float r; asm("v_rcp_f32 %0, %1" : "=v"(r) : "v"(x)); return r;
}

// ================= bf16 MFMA GEMM: C = [Cadd +] A @ BT^T + bias =================
template<bool HAS_BIAS, bool ADD_C, bool RELU, bool OUT_F32, bool OUT_BF16>
__global__ __launch_bounds__(256) void gemm_bf16mfma(
    const ushort* __restrict__ A, const ushort* __restrict__ BT,
    const float* __restrict__ bias, const float* __restrict__ Cadd,
    float* __restrict__ Cf, ushort* __restrict__ Cb,
    int M, int Nn, int K, int ldb, int coloff)
{
    __shared__ ushort As[128 * 64];
    __shared__ ushort Bs[128 * 64];
    const int tid = threadIdx.x;
    const int lane = tid & 63;
    const int wid = tid >> 6;
    const int wm = wid >> 1, wn = wid & 1;
    const int m0 = blockIdx.y * 128, n0 = blockIdx.x * 128;

    f32x4 acc[4][4] = {};

    const int srow = tid >> 3;
    const int schk = tid & 7;
    const char* AsB = (const char*)As;
    const char* BsB = (const char*)Bs;

    for (int k0 = 0; k0 < K; k0 += 64) {
#pragma unroll
        for (int i = 0; i < 4; ++i) {
            int row = i * 32 + srow;
            int ca = (schk ^ (row & 7)) * 8;
            gload_lds16(A + (size_t)(m0 + row) * K + k0 + ca,
                        (char*)As + i * 4096 + wid * 1024);
            gload_lds16(BT + (size_t)(n0 + row) * K + k0 + ca,
                        (char*)Bs + i * 4096 + wid * 1024);
        }
        __syncthreads();
#pragma unroll
        for (int kk = 0; kk < 2; ++kk) {
            const int kc = kk * 4 + (lane >> 4);
            bf16x8 af[4], bfr[4];
#pragma unroll
            for (int i = 0; i < 4; ++i) {
                int row = wm * 64 + i * 16 + (lane & 15);
                af[i] = *(const bf16x8*)(AsB + row * 128 + ((kc ^ (row & 7)) << 4));
            }
#pragma unroll
            for (int j = 0; j < 4; ++j) {
                int col = wn * 64 + j * 16 + (lane & 15);
                bfr[j] = *(const bf16x8*)(BsB + col * 128 + ((kc ^ (col & 7)) << 4));
            }
#pragma unroll
            for (int i = 0; i < 4; ++i)
#pragma unroll
                for (int j = 0; j < 4; ++j)
                    acc[i][j] = __builtin_amdgcn_mfma_f32_16x16x32_bf16(af[i], bfr[j], acc[i][j], 0, 0, 0);
        }
        __syncthreads();
    }

#pragma unroll
    for (int i = 0; i < 4; ++i) {
#pragma unroll
        for (int j = 0; j < 4; ++j) {
#pragma unroll
            for (int q = 0; q < 4; ++q) {
                int row = m0 + wm * 64 + i * 16 + (lane >> 4) * 4 + q;
                int col = n0 + wn * 64 + j * 16 + (lane & 15);
                float v = acc[i][j][q];
                if (HAS_BIAS) v += bias[col];
                if (ADD_C)    v += Cadd[(size_t)row * Nn + col];
                if (RELU)     v = fmaxf(v, 0.f);
                if (OUT_F32)  Cf[(size_t)row * Nn + col] = v;
                if (OUT_BF16) Cb[(size_t)row * ldb + col + coloff] = f2bf(v);
            }
        }
    }
}

// ========== fused first GEMM: A=h_bf [12288][512], BT=[WfT;WnT] [768][512] ==========
// cols 0..255   -> node_proj_s = (acc + bf)*TANH_C   (f32, pre-scaled for att)
// cols 256..767 -> A2[row][H1_OFF + col-256] = bf16(acc + bn)
__global__ __launch_bounds__(256) void gemm_fused_first(
    const ushort* __restrict__ A, const ushort* __restrict__ BT,
    const float* __restrict__ biasF, const float* __restrict__ biasN,
    float* __restrict__ node_proj_s, ushort* __restrict__ A2)
{
    __shared__ ushort As[128 * 64];
    __shared__ ushort Bs[128 * 64];
    const int K = DD_IN;
    const int tid = threadIdx.x;
    const int lane = tid & 63;
    const int wid = tid >> 6;
    const int wm = wid >> 1, wn = wid & 1;
    const int m0 = blockIdx.y * 128, n0 = blockIdx.x * 128;

    f32x4 acc[4][4] = {};

    const int srow = tid >> 3;
    const int schk = tid & 7;
    const char* AsB = (const char*)As;
    const char* BsB = (const char*)Bs;

    for (int k0 = 0; k0 < K; k0 += 64) {
#pragma unroll
        for (int i = 0; i < 4; ++i) {
            int row = i * 32 + srow;
            int ca = (schk ^ (row & 7)) * 8;
            gload_lds16(A + (size_t)(m0 + row) * K + k0 + ca,
                        (char*)As + i * 4096 + wid * 1024);
            gload_lds16(BT + (size_t)(n0 + row) * K + k0 + ca,
                        (char*)Bs + i * 4096 + wid * 1024);
        }
        __syncthreads();
#pragma unroll
        for (int kk = 0; kk < 2; ++kk) {
            const int kc = kk * 4 + (lane >> 4);
            bf16x8 af[4], bfr[4];
#pragma unroll
            for (int i = 0; i < 4; ++i) {
                int row = wm * 64 + i * 16 + (lane & 15);
                af[i] = *(const bf16x8*)(AsB + row * 128 + ((kc ^ (row & 7)) << 4));
            }
#pragma unroll
            for (int j = 0; j < 4; ++j) {
                int col = wn * 64 + j * 16 + (lane & 15);
                bfr[j] = *(const bf16x8*)(BsB + col * 128 + ((kc ^ (col & 7)) << 4));
            }
#pragma unroll
            for (int i = 0; i < 4; ++i)
#pragma unroll
                for (int j = 0; j < 4; ++j)
                    acc[i][j] = __builtin_amdgcn_mfma_f32_16x16x32_bf16(af[i], bfr[j], acc[i][j], 0, 0, 0);
        }
        __syncthreads();
    }

    if (n0 < 256) {
#pragma unroll
        for (int i = 0; i < 4; ++i)
#pragma unroll
            for (int j = 0; j < 4; ++j)
#pragma unroll
                for (int q = 0; q < 4; ++q) {
                    int row = m0 + wm * 64 + i * 16 + (lane >> 4) * 4 + q;
                    int col = n0 + wn * 64 + j * 16 + (lane & 15);
                    node_proj_s[(size_t)row * P_DIM + col] = (acc[i][j][q] + biasF[col]) * TANH_C;
                }
    } else {
#pragma unroll
        for (int i = 0; i < 4; ++i)
#pragma unroll
            for (int j = 0; j < 4; ++j)
#pragma unroll
                for (int q = 0; q < 4; ++q) {
                    int row = m0 + wm * 64 + i * 16 + (lane >> 4) * 4 + q;
                    int col = n0 - 256 + wn * 64 + j * 16 + (lane & 15);
                    A2[(size_t)row * A2_LD + H1_OFF + col] = f2bf(acc[i][j][q] + biasN[col]);
                }
    }
}

// ================= fp32 -> bf16 convert =================
__global__ __launch_bounds__(256) void cvt_f32_bf16(
    const float* __restrict__ in, ushort* __restrict__ out, int n4)
{
    int i = blockIdx.x * 256 + threadIdx.x;
    if (i >= n4) return;
    float4 v = ((const float4*)in)[i];
    ushort4v o;
    o[0] = f2bf(v.x); o[1] = f2bf(v.y); o[2] = f2bf(v.z); o[3] = f2bf(v.w);
    ((ushort4v*)out)[i] = o;
}

// ================= W [K][N] fp32 -> WT [N][K(ldt)] bf16 =================
__global__ __launch_bounds__(256) void transpose_cvt(
    const float* __restrict__ W, ushort* __restrict__ WT, int K, int N, int ldt)
{
    __shared__ float t[64][65];
    const int n0 = blockIdx.x * 64, k0 = blockIdx.y * 64;
    const int tx = threadIdx.x & 15, ty = threadIdx.x >> 4;
#pragma unroll
    for (int r = 0; r < 4; ++r) {
        float4 v = *(const float4*)&W[(size_t)(k0 + ty * 4 + r) * N + n0 + tx * 4];
        t[ty * 4 + r][tx * 4 + 0] = v.x;
        t[ty * 4 + r][tx * 4 + 1] = v.y;
        t[ty * 4 + r][tx * 4 + 2] = v.z;
        t[ty * 4 + r][tx * 4 + 3] = v.w;
    }
    __syncthreads();
    const int nl = threadIdx.x >> 2, kq = (threadIdx.x & 3) * 16;
    ushort u[16] __attribute__((aligned(16)));
#pragma unroll
    for (int c = 0; c < 16; ++c) u[c] = f2bf(t[kq + c][nl]);
    ushort* d = &WT[(size_t)(n0 + nl) * ldt + k0 + kq];
    *(ushort8v*)d = *(ushort8v*)&u[0];
    *(ushort8v*)(d + 8) = *(ushort8v*)&u[8];
}

// ================= b' = bap + bim @ Wap1 =================
__global__ __launch_bounds__(256) void bprime_kernel(
    const float* __restrict__ bim, const float* __restrict__ Wap,
    const float* __restrict__ bap, float* __restrict__ bp)
{
    int n = blockIdx.x * 256 + threadIdx.x;
    float s = bap[n];
    for (int k = 0; k < DD_OUT; ++k) s += bim[k] * Wap[(size_t)k * DD_OUT + n];
    bp[n] = s;
}

// ================= attention logits + softmax =================
__global__ __launch_bounds__(128, 4) void att_kernel(
    const float* __restrict__ node_proj_s, const float* __restrict__ img_proj,
    const int* __restrict__ batch_ids, const float* __restrict__ Wa,
    float* __restrict__ att)
{
    __shared__ float red[2][R_REG][68];
    const int wv = threadIdx.x >> 6;
    const int n = blockIdx.x * 2 + wv;
    const int lane = threadIdx.x & 63;
    const int b = batch_ids[n];

    const float4 nps = *(const float4*)(node_proj_s + (size_t)n * P_DIM + 4 * lane);
    const float4 wa = *(const float4*)(Wa + 4 * lane);
    const float* ip0 = img_proj + (size_t)b * R_REG * P_DIM + 4 * lane;

#pragma unroll
    for (int r = 0; r < R_REG; ++r) {
        float4 ip = *(const float4*)(ip0 + (size_t)r * P_DIM);
        float t0 = fexp2(fmaf(ip.x, TANH_C, nps.x));
        float t1 = fexp2(fmaf(ip.y, TANH_C, nps.y));
        float t2 = fexp2(fmaf(ip.z, TANH_C, nps.z));
        float t3 = fexp2(fmaf(ip.w, TANH_C, nps.w));
        float p;
        p = wa.x * frcp(t0 + 1.f);
        p = fmaf(wa.y, frcp(t1 + 1.f), p);
        p = fmaf(wa.z, frcp(t2 + 1.f), p);
        p = fmaf(wa.w, frcp(t3 + 1.f), p);
        red[wv][r][lane] = p;
    }
    __syncthreads();

    float logit = -INFINITY;
    if (lane < R_REG) {
        const float* row = &red[wv][lane][0];
        float4 s4 = *(const float4*)row;
#pragma unroll
        for (int c = 4; c < 64; c += 4) {
            float4 v = *(const float4*)(row + c);
            s4.x += v.x; s4.y += v.y; s4.z += v.z; s4.w += v.w;
        }
        logit = -2.f * ((s4.x + s4.y) + (s4.z + s4.w));
    }
    float m = logit;
#pragma unroll
    for (int off = 32; off; off >>= 1) m = fmaxf(m, __shfl_xor(m, off));
    float e = (lane < R_REG) ? __expf(logit - m) : 0.f;
    float s = e;
#pragma unroll
    for (int off = 32; off; off >>= 1) s += __shfl_xor(s, off);
    if (lane < R_REG) att[(size_t)n * R_REG + lane] = e / s;
}

// ================= batched attended image feature -> A2 img cols =================
#define IA_SLICES 8
__global__ __launch_bounds__(256) void img_att_batched(
    const float* __restrict__ att, const float* __restrict__ img_feats,
    const int* __restrict__ boffs, const int* __restrict__ nlist,
    ushort* __restrict__ A2)
{
    const int b     = blockIdx.x & 63;
    const int chunk = (blockIdx.x >> 6) & 1;
    const int slice = blockIdx.x >> 7;
    const int t = threadIdx.x;
    const int c0 = chunk * 512 + 2 * t;

    const int ns = boffs[b], ne = boffs[b + 1];
    const int cnt = ne - ns;
    const int per = (cnt + IA_SLICES - 1) / IA_SLICES;
    const int i0 = ns + slice * per;
    const int i1 = min(i0 + per, ne);
    if (i0 >= i1) return;

    float2 col[R_REG];
    const float* base = img_feats + (size_t)b * R_REG * D_IMG + c0;
#pragma unroll
    for (int r = 0; r < R_REG; ++r)
        col[r] = *(const float2*)(base + (size_t)r * D_IMG);

    __shared__ float att_s[8][R_REG];
    for (int i = i0; i < i1; i += 8) {
        int g = min(8, i1 - i);
        __syncthreads();
        for (int idx = t; idx < g * R_REG; idx += 256) {
            int j = idx / R_REG, r = idx - j * R_REG;
            att_s[j][r] = att[(size_t)nlist[i + j] * R_REG + r];
        }
        __syncthreads();
        for (int j = 0; j < g; ++j) {
            float4 av[9];
#pragma unroll
            for (int q = 0; q < 9; ++q) av[q] = *(const float4*)&att_s[j][q * 4];
            float ax = 0.f, ay = 0.f;
#pragma unroll
            for (int r = 0; r < R_REG; ++r) {
                float a = (r & 2) ? ((r & 1) ? av[r >> 2].w : av[r >> 2].z)
                                  : ((r & 1) ? av[r >> 2].y : av[r >> 2].x);
                ax += a * col[r].x;
                ay += a * col[r].y;
            }
            ushort2 o; o.x = f2bf(ax); o.y = f2bf(ay);
            *(ushort2*)&A2[(size_t)nlist[i + j] * A2_LD + IMG_OFF + c0] = o;
        }
    }
}

// ================= counting sorts =================
__global__ __launch_bounds__(256) void count_deg(const int* __restrict__ dst, int* __restrict__ deg) {
    int i = blockIdx.x * 256 + threadIdx.x;
    if (i < E_EDGES) atomicAdd(&deg[dst[i]], 1);
}

__global__ __launch_bounds__(256) void scan_deg(const int* __restrict__ deg, int* __restrict__ off) {
    __shared__ int s[257];
    const int t = threadIdx.x;
    const int base = t * 48;
    int sum = 0;
    for (int j = 0; j < 48; ++j) sum += deg[base + j];
    s[t] = sum;
    __syncthreads();
    if (t == 0) {
        int acc = 0;
        for (int i = 0; i < 256; ++i) { int v = s[i]; s[i] = acc; acc += v; }
        s[256] = acc;
    }
    __syncthreads();
    int run = s[t];
    for (int j = 0; j < 48; ++j) { off[base + j] = run; run += deg[base + j]; }
    if (t == 255) off[N_NODES] = s[256];
}

__global__ __launch_bounds__(256) void scatter_edges(
    const int* __restrict__ src, const int* __restrict__ dst,
    const int* __restrict__ off, int* __restrict__ cur, int* __restrict__ ssrc)
{
    int i = blockIdx.x * 256 + threadIdx.x;
    if (i < E_EDGES) {
        int d = dst[i];
        int p = off[d] + atomicAdd(&cur[d], 1);
        ssrc[p] = src[i];
    }
}

__global__ __launch_bounds__(256) void count_batch(const int* __restrict__ bid, int* __restrict__ bcnt) {
    int i = blockIdx.x * 256 + threadIdx.x;
    if (i < N_NODES) atomicAdd(&bcnt[bid[i]], 1);
}

__global__ __launch_bounds__(64) void scan_batch(const int* __restrict__ bcnt, int* __restrict__ boffs) {
    if (threadIdx.x == 0) {
        int acc = 0;
        for (int i = 0; i < B_EX; ++i) { boffs[i] = acc; acc += bcnt[i]; }
        boffs[B_EX] = acc;
    }
}

__global__ __launch_bounds__(256) void scatter_batch(
    const int* __restrict__ bid, const int* __restrict__ boffs,
    int* __restrict__ bcur, int* __restrict__ nlist)
{
    int i = blockIdx.x * 256 + threadIdx.x;
    if (i < N_NODES) {
        int b = bid[i];
        int p = boffs[b] + atomicAdd(&bcur[b], 1);
        nlist[p] = i;
    }
}

// ================= CSR gather: wave per node, lane = 8 cols (uint4), unroll x2 ====
__device__ __forceinline__ void acc8(float* a, uint4 v) {
    a[0] += bf2f((ushort)(v.x & 0xffffu)); a[1] += bf2f((ushort)(v.x >> 16));
    a[2] += bf2f((ushort)(v.y & 0xffffu)); a[3] += bf2f((ushort)(v.y >> 16));
    a[4] += bf2f((ushort)(v.z & 0xffffu)); a[5] += bf2f((ushort)(v.z >> 16));
    a[6] += bf2f((ushort)(v.w & 0xffffu)); a[7] += bf2f((ushort)(v.w >> 16));
}

__global__ __launch_bounds__(256) void gather_neigh(
    const int* __restrict__ off, const int* __restrict__ ssrc,
    const ushort* __restrict__ A2h1 /* A2 + H1_OFF */,
    ushort* __restrict__ A2nb /* A2 + NEIGH_OFF */)
{
    const int wv = threadIdx.x >> 6;
    const int n = blockIdx.x * 4 + wv;
    const int lane = threadIdx.x & 63;
    const int e0 = off[n], e1 = off[n + 1];

    float a[8] = {};
    int e = e0;
    for (; e + 2 <= e1; e += 2) {
        int s0 = ssrc[e], s1 = ssrc[e + 1];
        uint4 v0 = *(const uint4*)(A2h1 + (size_t)s0 * A2_LD + lane * 8);
        uint4 v1 = *(const uint4*)(A2h1 + (size_t)s1 * A2_LD + lane * 8);
        acc8(a, v0);
        acc8(a, v1);
    }
    if (e < e1) {
        int s0 = ssrc[e];
        uint4 v0 = *(const uint4*)(A2h1 + (size_t)s0 * A2_LD + lane * 8);
        acc8(a, v0);
    }
    ushort8v o;
#pragma unroll
    for (int i = 0; i < 8; ++i) o[i] = f2bf(a[i]);
    *(ushort8v*)(A2nb + (size_t)n * A2_LD + lane * 8) = o;
}

extern "C" void kernel_launch(void* const* d_in, const int* in_sizes, int n_in,
                              void* d_out, int out_size, void* d_ws, size_t ws_size,
                              hipStream_t stream) {
    const float* h         = (const float*)d_in[0];
    const float* img_feats = (const float*)d_in[1];
    const int*   batch_ids = (const int*)d_in[2];
    const int*   src       = (const int*)d_in[3];
    const int*   dst       = (const int*)d_in[4];
    const float* Wf  = (const float*)d_in[5];
    const float* bf  = (const float*)d_in[6];
    const float* Wi  = (const float*)d_in[7];
    const float* bi  = (const float*)d_in[8];
    const float* Wa  = (const float*)d_in[9];
    // d_in[10] = ba: constant logit shift, cancels in softmax
    const float* Wn  = (const float*)d_in[11];
    const float* bn  = (const float*)d_in[12];
    const float* Wim = (const float*)d_in[13];
    const float* bim = (const float*)d_in[14];
    const float* Wap = (const float*)d_in[15];
    const float* bap = (const float*)d_in[16];
    float* out = (float*)d_out;
    float* ws  = (float*)d_ws;

    // ---- workspace layout (offsets in 4-byte units) ----
    ushort* h_bf    = (ushort*)(ws + 0);          // [12288][512] bf16
    ushort* A2      = (ushort*)(ws + 3145728);    // [12288][2048] bf16: img|neigh|h1
    float*  node_proj = ws + 15728640;            // [12288][256] f32 (pre-scaled)
    float*  img_proj  = ws + 18874368;            // [2304][256]  f32
    ushort* imgf_bf   = (ushort*)(ws + 19464192); // [2304][1024] bf16
    float*  att       = ws + 20643840;            // [12288][36]  f32
    ushort* WfnT  = (ushort*)(ws + 21086208);     // [768][512]: rows 0-255 Wf^T, 256-767 Wn^T
    ushort* WiT   = (ushort*)(ws + 21282816);     // [256][1024]
    ushort* Wim_bf= (ushort*)(ws + 21413888);     // [1024][512] bf16 (row-major copy)
    ushort* Wap1T = (ushort*)(ws + 21676032);     // [512][512]
    ushort* BT2   = (ushort*)(ws + 21807104);     // [512][2048]: W'^T | Wap1^T | Wap2^T
    float*  bprime = ws + 22331392;               // [512]
    int* deg  = (int*)(ws + 22331904);            // [12288]
    int* cur  = deg + N_NODES;                    // [12288]
    int* offs = cur + N_NODES;                    // [12289]
    int* ssrc = offs + N_NODES + 1;               // [196608]
    int* bcnt = ssrc + E_EDGES;                   // [64]
    int* bcur = bcnt + B_EX;                      // [64]
    int* boffs = bcur + B_EX;                     // [65]
    int* nlist = boffs + B_EX + 1;                // [12288]

    dim3 blk(256);

    // ---- converts & weight transposes ----
    cvt_f32_bf16<<<dim3(N_NODES * DD_IN / 4 / 256), blk, 0, stream>>>(h, h_bf, N_NODES * DD_IN / 4);
    cvt_f32_bf16<<<dim3(B_EX * R_REG * D_IMG / 4 / 256), blk, 0, stream>>>(img_feats, imgf_bf, B_EX * R_REG * D_IMG / 4);
    cvt_f32_bf16<<<dim3(D_IMG * DD_OUT / 4 / 256), blk, 0, stream>>>(Wim, Wim_bf, D_IMG * DD_OUT / 4);
    transpose_cvt<<<dim3(P_DIM / 64, DD_IN / 64), blk, 0, stream>>>(Wf, WfnT, DD_IN, P_DIM, DD_IN);
    transpose_cvt<<<dim3(DD_OUT / 64, DD_IN / 64), blk, 0, stream>>>(Wn, WfnT + (size_t)P_DIM * DD_IN, DD_IN, DD_OUT, DD_IN);
    transpose_cvt<<<dim3(P_DIM / 64, D_IMG / 64), blk, 0, stream>>>(Wi, WiT, D_IMG, P_DIM, D_IMG);
    transpose_cvt<<<dim3(DD_OUT / 64, DD_OUT / 64), blk, 0, stream>>>(Wap, Wap1T, DD_OUT, DD_OUT, DD_OUT);
    transpose_cvt<<<dim3(DD_OUT / 64, DD_OUT / 64), blk, 0, stream>>>(Wap, BT2 + NEIGH_OFF, DD_OUT, DD_OUT, A2_LD);
    transpose_cvt<<<dim3(DD_OUT / 64, DD_OUT / 64), blk, 0, stream>>>(Wap + (size_t)DD_OUT * DD_OUT, BT2 + H1_OFF, DD_OUT, DD_OUT, A2_LD);

    // ---- CSR build (edges by dst) + node sort by batch ----
    hipMemsetAsync(deg, 0, 2 * N_NODES * sizeof(int), stream);
    hipMemsetAsync(bcnt, 0, 2 * B_EX * sizeof(int), stream);
    count_deg<<<dim3(E_EDGES / 256), blk, 0, stream>>>(dst, deg);
    scan_deg<<<dim3(1), blk, 0, stream>>>(deg, offs);
    scatter_edges<<<dim3(E_EDGES / 256), blk, 0, stream>>>(src, dst, offs, cur, ssrc);
    count_batch<<<dim3(N_NODES / 256), blk, 0, stream>>>(batch_ids, bcnt);
    scan_batch<<<dim3(1), dim3(64), 0, stream>>>(bcnt, boffs);
    scatter_batch<<<dim3(N_NODES / 256), blk, 0, stream>>>(batch_ids, boffs, bcur, nlist);

    // ---- W'^T = Wap1^T @ Wim^T  -> BT2 cols 0..1023 ----
    gemm_bf16mfma<false, false, false, false, true><<<dim3(D_IMG / 128, DD_OUT / 128), blk, 0, stream>>>(
        Wap1T, Wim_bf, nullptr, nullptr, nullptr, BT2, DD_OUT, D_IMG, DD_OUT, A2_LD, 0);
    // ---- b' = bap + bim @ Wap1 ----
    bprime_kernel<<<dim3(DD_OUT / 256), blk, 0, stream>>>(bim, Wap, bap, bprime);

    // ---- fused: node_proj_s (scaled) + h1 -> A2 h1 cols ----
    gemm_fused_first<<<dim3((P_DIM + DD_OUT) / 128, N_NODES / 128), blk, 0, stream>>>(
        h_bf, WfnT, bf, bn, node_proj, A2);
    // ---- img_proj = img_feats @ Wi + bi ----
    gemm_bf16mfma<true, false, false, true, false><<<dim3(P_DIM / 128, (B_EX * R_REG) / 128), blk, 0, stream>>>(
        imgf_bf, WiT, bi, nullptr, img_proj, nullptr, B_EX * R_REG, P_DIM, D_IMG, 0, 0);
    // ---- attention ----
    att_kernel<<<dim3(N_NODES / 2), dim3(128), 0, stream>>>(node_proj, img_proj, batch_ids, Wa, att);
    img_att_batched<<<dim3(B_EX * 2 * IA_SLICES), blk, 0, stream>>>(att, img_feats, boffs, nlist, A2);
    // ---- neigh = segment_sum(h1[src], dst) -> A2 neigh cols ----
    gather_neigh<<<dim3(N_NODES / 4), blk, 0, stream>>>(offs, ssrc, A2 + H1_OFF, A2 + NEIGH_OFF);
    // ---- out = relu(A2 @ [W'; Wap1; Wap2] + b') ----
    gemm_bf16mfma<true, false, true, true, false><<<dim3(DD_OUT / 128, N_NODES / 128), blk, 0, stream>>>(
        A2, BT2, bprime, nullptr, out, nullptr, N_NODES, DD_OUT, 2048, 0, 0);
}

// Round 7
// 254.208 us; speedup vs baseline: 1.1964x; 1.1964x over previous
//
#include <hip/hip_runtime.h>
#include <cstdint>
#include <cstddef>

#define N_NODES 12288
#define B_EX    64
#define R_REG   36
#define E_EDGES 196608
#define DD_IN   512
#define DD_OUT  512
#define P_DIM   256
#define D_IMG   1024
#define TANH_C  2.885390081777927f   // 2*log2(e)

// A2 concatenated GEMM operand: [12288][2048] bf16
#define A2_LD     2048
#define IMG_OFF   0
#define NEIGH_OFF 1024
#define H1_OFF    1536

typedef unsigned short ushort;
typedef __bf16 bf16x8 __attribute__((ext_vector_type(8)));
typedef float f32x4 __attribute__((ext_vector_type(4)));
typedef ushort ushort4v __attribute__((ext_vector_type(4)));
typedef ushort ushort8v __attribute__((ext_vector_type(8)));

__device__ __forceinline__ ushort f2bf(float f) {
    uint32_t u = __float_as_uint(f);
    uint32_t r = (u + 0x7fffu + ((u >> 16) & 1u)) >> 16;
    return (ushort)r;
}
__device__ __forceinline__ float bf2f(ushort u) {
    return __uint_as_float(((uint32_t)u) << 16);
}
__device__ __forceinline__ void gload_lds16(const void* g, void* l) {
    __builtin_amdgcn_global_load_lds((const __attribute__((address_space(1))) void*)g,
                                     (__attribute__((address_space(3))) void*)l, 16, 0, 0);
}
__device__ __forceinline__ float fexp2(float x) {
    float r; asm("v_exp_f32 %0, %1" : "=v"(r) : "v"(x)); return r;
}
__device__ __forceinline__ float frcp(float x) {
    float r; asm("v_rcp_f32 %0, %1" : "=v"(r) : "v"(x)); return r;
}
// bijective XCD swizzle for nwg % 8 == 0 (identity otherwise)
__device__ __forceinline__ int xcd_swz(int lin, int nwg) {
    if ((nwg & 7) == 0) return (lin & 7) * (nwg >> 3) + (lin >> 3);
    return lin;
}

// ================= bf16 MFMA GEMM: C = [Cadd +] A @ BT^T + bias =================
template<bool HAS_BIAS, bool ADD_C, bool RELU, bool OUT_F32, bool OUT_BF16>
__global__ __launch_bounds__(256) void gemm_bf16mfma(
    const ushort* __restrict__ A, const ushort* __restrict__ BT,
    const float* __restrict__ bias, const float* __restrict__ Cadd,
    float* __restrict__ Cf, ushort* __restrict__ Cb,
    int M, int Nn, int K, int ldb, int coloff)
{
    __shared__ ushort As[128 * 64];
    __shared__ ushort Bs[128 * 64];
    const int tid = threadIdx.x;
    const int lane = tid & 63;
    const int wid = tid >> 6;
    const int wm = wid >> 1, wn = wid & 1;
    const int nx = gridDim.x;
    const int lin = xcd_swz(blockIdx.y * nx + blockIdx.x, nx * gridDim.y);
    const int m0 = (lin / nx) * 128, n0 = (lin % nx) * 128;

    f32x4 acc[4][4] = {};

    const int srow = tid >> 3;
    const int schk = tid & 7;
    const char* AsB = (const char*)As;
    const char* BsB = (const char*)Bs;

    for (int k0 = 0; k0 < K; k0 += 64) {
#pragma unroll
        for (int i = 0; i < 4; ++i) {
            int row = i * 32 + srow;
            int ca = (schk ^ (row & 7)) * 8;
            gload_lds16(A + (size_t)(m0 + row) * K + k0 + ca,
                        (char*)As + i * 4096 + wid * 1024);
            gload_lds16(BT + (size_t)(n0 + row) * K + k0 + ca,
                        (char*)Bs + i * 4096 + wid * 1024);
        }
        __syncthreads();
#pragma unroll
        for (int kk = 0; kk < 2; ++kk) {
            const int kc = kk * 4 + (lane >> 4);
            bf16x8 af[4], bfr[4];
#pragma unroll
            for (int i = 0; i < 4; ++i) {
                int row = wm * 64 + i * 16 + (lane & 15);
                af[i] = *(const bf16x8*)(AsB + row * 128 + ((kc ^ (row & 7)) << 4));
            }
#pragma unroll
            for (int j = 0; j < 4; ++j) {
                int col = wn * 64 + j * 16 + (lane & 15);
                bfr[j] = *(const bf16x8*)(BsB + col * 128 + ((kc ^ (col & 7)) << 4));
            }
#pragma unroll
            for (int i = 0; i < 4; ++i)
#pragma unroll
                for (int j = 0; j < 4; ++j)
                    acc[i][j] = __builtin_amdgcn_mfma_f32_16x16x32_bf16(af[i], bfr[j], acc[i][j], 0, 0, 0);
        }
        __syncthreads();
    }

#pragma unroll
    for (int i = 0; i < 4; ++i) {
#pragma unroll
        for (int j = 0; j < 4; ++j) {
#pragma unroll
            for (int q = 0; q < 4; ++q) {
                int row = m0 + wm * 64 + i * 16 + (lane >> 4) * 4 + q;
                int col = n0 + wn * 64 + j * 16 + (lane & 15);
                float v = acc[i][j][q];
                if (HAS_BIAS) v += bias[col];
                if (ADD_C)    v += Cadd[(size_t)row * Nn + col];
                if (RELU)     v = fmaxf(v, 0.f);
                if (OUT_F32)  Cf[(size_t)row * Nn + col] = v;
                if (OUT_BF16) Cb[(size_t)row * ldb + col + coloff] = f2bf(v);
            }
        }
    }
}

// ========== specialized final GEMM: out = relu(A2 @ BT2^T + b'), BM=128 BN=64 ==========
// grid (8, 96) = 768 blocks = exactly 3/CU. K = 2048.
__global__ __launch_bounds__(256) void gemm_out(
    const ushort* __restrict__ A, const ushort* __restrict__ BT,
    const float* __restrict__ bias, float* __restrict__ Cf)
{
    __shared__ ushort As[128 * 64];
    __shared__ ushort Bs[64 * 64];
    const int K = A2_LD;
    const int tid = threadIdx.x;
    const int lane = tid & 63;
    const int wid = tid >> 6;
    const int lin = xcd_swz(blockIdx.y * 8 + blockIdx.x, 768);
    const int m0 = (lin >> 3) * 128, n0 = (lin & 7) * 64;

    f32x4 acc[2][4] = {};

    const int srow = tid >> 3;
    const int schk = tid & 7;
    const char* AsB = (const char*)As;
    const char* BsB = (const char*)Bs;

    for (int k0 = 0; k0 < K; k0 += 64) {
#pragma unroll
        for (int i = 0; i < 4; ++i) {
            int row = i * 32 + srow;
            int ca = (schk ^ (row & 7)) * 8;
            gload_lds16(A + (size_t)(m0 + row) * K + k0 + ca,
                        (char*)As + i * 4096 + wid * 1024);
        }
#pragma unroll
        for (int i = 0; i < 2; ++i) {
            int row = i * 32 + srow;
            int cb = (schk ^ (row & 7)) * 8;
            gload_lds16(BT + (size_t)(n0 + row) * K + k0 + cb,
                        (char*)Bs + i * 4096 + wid * 1024);
        }
        __syncthreads();
#pragma unroll
        for (int kk = 0; kk < 2; ++kk) {
            const int kc = kk * 4 + (lane >> 4);
            bf16x8 af[2], bfr[4];
#pragma unroll
            for (int i = 0; i < 2; ++i) {
                int row = wid * 32 + i * 16 + (lane & 15);
                af[i] = *(const bf16x8*)(AsB + row * 128 + ((kc ^ (row & 7)) << 4));
            }
#pragma unroll
            for (int j = 0; j < 4; ++j) {
                int col = j * 16 + (lane & 15);
                bfr[j] = *(const bf16x8*)(BsB + col * 128 + ((kc ^ (col & 7)) << 4));
            }
#pragma unroll
            for (int i = 0; i < 2; ++i)
#pragma unroll
                for (int j = 0; j < 4; ++j)
                    acc[i][j] = __builtin_amdgcn_mfma_f32_16x16x32_bf16(af[i], bfr[j], acc[i][j], 0, 0, 0);
        }
        __syncthreads();
    }

#pragma unroll
    for (int i = 0; i < 2; ++i) {
#pragma unroll
        for (int j = 0; j < 4; ++j) {
#pragma unroll
            for (int q = 0; q < 4; ++q) {
                int row = m0 + wid * 32 + i * 16 + (lane >> 4) * 4 + q;
                int col = n0 + j * 16 + (lane & 15);
                float v = fmaxf(acc[i][j][q] + bias[col], 0.f);
                Cf[(size_t)row * DD_OUT + col] = v;
            }
        }
    }
}

// ========== fused first GEMM: A=h_bf [12288][512], BT=[WfT;WnT] [768][512] ==========
__global__ __launch_bounds__(256) void gemm_fused_first(
    const ushort* __restrict__ A, const ushort* __restrict__ BT,
    const float* __restrict__ biasF, const float* __restrict__ biasN,
    float* __restrict__ node_proj_s, ushort* __restrict__ A2)
{
    __shared__ ushort As[128 * 64];
    __shared__ ushort Bs[128 * 64];
    const int K = DD_IN;
    const int tid = threadIdx.x;
    const int lane = tid & 63;
    const int wid = tid >> 6;
    const int wm = wid >> 1, wn = wid & 1;
    const int nx = gridDim.x;
    const int lin = xcd_swz(blockIdx.y * nx + blockIdx.x, nx * gridDim.y);
    const int m0 = (lin / nx) * 128, n0 = (lin % nx) * 128;

    f32x4 acc[4][4] = {};

    const int srow = tid >> 3;
    const int schk = tid & 7;
    const char* AsB = (const char*)As;
    const char* BsB = (const char*)Bs;

    for (int k0 = 0; k0 < K; k0 += 64) {
#pragma unroll
        for (int i = 0; i < 4; ++i) {
            int row = i * 32 + srow;
            int ca = (schk ^ (row & 7)) * 8;
            gload_lds16(A + (size_t)(m0 + row) * K + k0 + ca,
                        (char*)As + i * 4096 + wid * 1024);
            gload_lds16(BT + (size_t)(n0 + row) * K + k0 + ca,
                        (char*)Bs + i * 4096 + wid * 1024);
        }
        __syncthreads();
#pragma unroll
        for (int kk = 0; kk < 2; ++kk) {
            const int kc = kk * 4 + (lane >> 4);
            bf16x8 af[4], bfr[4];
#pragma unroll
            for (int i = 0; i < 4; ++i) {
                int row = wm * 64 + i * 16 + (lane & 15);
                af[i] = *(const bf16x8*)(AsB + row * 128 + ((kc ^ (row & 7)) << 4));
            }
#pragma unroll
            for (int j = 0; j < 4; ++j) {
                int col = wn * 64 + j * 16 + (lane & 15);
                bfr[j] = *(const bf16x8*)(BsB + col * 128 + ((kc ^ (col & 7)) << 4));
            }
#pragma unroll
            for (int i = 0; i < 4; ++i)
#pragma unroll
                for (int j = 0; j < 4; ++j)
                    acc[i][j] = __builtin_amdgcn_mfma_f32_16x16x32_bf16(af[i], bfr[j], acc[i][j], 0, 0, 0);
        }
        __syncthreads();
    }

    if (n0 < 256) {
#pragma unroll
        for (int i = 0; i < 4; ++i)
#pragma unroll
            for (int j = 0; j < 4; ++j)
#pragma unroll
                for (int q = 0; q < 4; ++q) {
                    int row = m0 + wm * 64 + i * 16 + (lane >> 4) * 4 + q;
                    int col = n0 + wn * 64 + j * 16 + (lane & 15);
                    node_proj_s[(size_t)row * P_DIM + col] = (acc[i][j][q] + biasF[col]) * TANH_C;
                }
    } else {
#pragma unroll
        for (int i = 0; i < 4; ++i)
#pragma unroll
            for (int j = 0; j < 4; ++j)
#pragma unroll
                for (int q = 0; q < 4; ++q) {
                    int row = m0 + wm * 64 + i * 16 + (lane >> 4) * 4 + q;
                    int col = n0 - 256 + wn * 64 + j * 16 + (lane & 15);
                    A2[(size_t)row * A2_LD + H1_OFF + col] = f2bf(acc[i][j][q] + biasN[col]);
                }
    }
}

// ================= fused fp32 -> bf16 converts (h, img_feats, Wim) =================
#define CVT_N1 (N_NODES * DD_IN / 4)
#define CVT_N2 (CVT_N1 + B_EX * R_REG * D_IMG / 4)
#define CVT_N3 (CVT_N2 + D_IMG * DD_OUT / 4)
__global__ __launch_bounds__(256) void cvt_all(
    const float* __restrict__ h, const float* __restrict__ imgf,
    const float* __restrict__ Wim,
    ushort* __restrict__ h_bf, ushort* __restrict__ imgf_bf, ushort* __restrict__ Wim_bf)
{
    int i = blockIdx.x * 256 + threadIdx.x;
    const float4* src; ushort4v* dst; int j;
    if (i < CVT_N1)      { src = (const float4*)h;    dst = (ushort4v*)h_bf;    j = i; }
    else if (i < CVT_N2) { src = (const float4*)imgf; dst = (ushort4v*)imgf_bf; j = i - CVT_N1; }
    else                 { src = (const float4*)Wim;  dst = (ushort4v*)Wim_bf;  j = i - CVT_N2; }
    float4 v = src[j];
    ushort4v o;
    o[0] = f2bf(v.x); o[1] = f2bf(v.y); o[2] = f2bf(v.z); o[3] = f2bf(v.w);
    dst[j] = o;
}

// ================= batched weight transposes (all 6 in one launch) =================
// tiles: [0,32) Wf->WfnT | [32,96) Wn->WfnT+256*512 | [96,160) Wi->WiT
//        [160,224) Wap1->Wap1T | [224,288) Wap1->BT2+NEIGH | [288,352) Wap2->BT2+H1
__global__ __launch_bounds__(256) void transpose_all(
    const float* __restrict__ Wf, const float* __restrict__ Wn,
    const float* __restrict__ Wi, const float* __restrict__ Wap,
    ushort* __restrict__ WfnT, ushort* __restrict__ WiT,
    ushort* __restrict__ Wap1T, ushort* __restrict__ BT2)
{
    int t = blockIdx.x;
    const float* W; ushort* WT; int N, ldt, gx;
    if (t < 32)       { W = Wf;  WT = WfnT;                        N = 256; ldt = 512;  gx = 4; }
    else if (t < 96)  { W = Wn;  WT = WfnT + 256 * 512;            N = 512; ldt = 512;  gx = 8; t -= 32; }
    else if (t < 160) { W = Wi;  WT = WiT;                         N = 256; ldt = 1024; gx = 4; t -= 96; }
    else if (t < 224) { W = Wap; WT = Wap1T;                       N = 512; ldt = 512;  gx = 8; t -= 160; }
    else if (t < 288) { W = Wap; WT = BT2 + NEIGH_OFF;             N = 512; ldt = 2048; gx = 8; t -= 224; }
    else              { W = Wap + 512 * 512; WT = BT2 + H1_OFF;    N = 512; ldt = 2048; gx = 8; t -= 288; }
    const int n0 = (t % gx) * 64, k0 = (t / gx) * 64;

    __shared__ float tt[64][65];
    const int tx = threadIdx.x & 15, ty = threadIdx.x >> 4;
#pragma unroll
    for (int r = 0; r < 4; ++r) {
        float4 v = *(const float4*)&W[(size_t)(k0 + ty * 4 + r) * N + n0 + tx * 4];
        tt[ty * 4 + r][tx * 4 + 0] = v.x;
        tt[ty * 4 + r][tx * 4 + 1] = v.y;
        tt[ty * 4 + r][tx * 4 + 2] = v.z;
        tt[ty * 4 + r][tx * 4 + 3] = v.w;
    }
    __syncthreads();
    const int nl = threadIdx.x >> 2, kq = (threadIdx.x & 3) * 16;
    ushort u[16] __attribute__((aligned(16)));
#pragma unroll
    for (int c = 0; c < 16; ++c) u[c] = f2bf(tt[kq + c][nl]);
    ushort* d = &WT[(size_t)(n0 + nl) * ldt + k0 + kq];
    *(ushort8v*)d = *(ushort8v*)&u[0];
    *(ushort8v*)(d + 8) = *(ushort8v*)&u[8];
}

// ================= fused counting (edges by dst + nodes by batch) =================
__global__ __launch_bounds__(256) void count_all(
    const int* __restrict__ dst, const int* __restrict__ bid,
    int* __restrict__ deg, int* __restrict__ bcnt)
{
    int b = blockIdx.x;
    if (b < E_EDGES / 256) {
        atomicAdd(&deg[dst[b * 256 + threadIdx.x]], 1);
    } else {
        atomicAdd(&bcnt[bid[(b - E_EDGES / 256) * 256 + threadIdx.x]], 1);
    }
}

// ================= fused scans + bprime =================
// block 0: deg scan -> offs; block 1: batch scan -> boffs; blocks 2,3: b' = bap + bim@Wap1
__global__ __launch_bounds__(256) void scan_all(
    const int* __restrict__ deg, int* __restrict__ offs,
    const int* __restrict__ bcnt, int* __restrict__ boffs,
    const float* __restrict__ bim, const float* __restrict__ Wap,
    const float* __restrict__ bap, float* __restrict__ bp)
{
    const int t = threadIdx.x;
    if (blockIdx.x == 0) {
        __shared__ int s[257];
        const int base = t * 48;
        int sum = 0;
        for (int j = 0; j < 48; ++j) sum += deg[base + j];
        s[t] = sum;
        __syncthreads();
        if (t == 0) {
            int acc = 0;
            for (int i = 0; i < 256; ++i) { int v = s[i]; s[i] = acc; acc += v; }
            s[256] = acc;
        }
        __syncthreads();
        int run = s[t];
        for (int j = 0; j < 48; ++j) { offs[base + j] = run; run += deg[base + j]; }
        if (t == 255) offs[N_NODES] = s[256];
    } else if (blockIdx.x == 1) {
        if (t == 0) {
            int acc = 0;
            for (int i = 0; i < B_EX; ++i) { boffs[i] = acc; acc += bcnt[i]; }
            boffs[B_EX] = acc;
        }
    } else {
        int n = (blockIdx.x - 2) * 256 + t;
        float s = bap[n];
        for (int k = 0; k < DD_OUT; ++k) s += bim[k] * Wap[(size_t)k * DD_OUT + n];
        bp[n] = s;
    }
}

// ================= fused scatter (edges + nodes) =================
__global__ __launch_bounds__(256) void scatter_all(
    const int* __restrict__ src, const int* __restrict__ dst,
    const int* __restrict__ offs, int* __restrict__ cur, int* __restrict__ ssrc,
    const int* __restrict__ bid, const int* __restrict__ boffs,
    int* __restrict__ bcur, int* __restrict__ nlist)
{
    int b = blockIdx.x;
    if (b < E_EDGES / 256) {
        int i = b * 256 + threadIdx.x;
        int d = dst[i];
        int p = offs[d] + atomicAdd(&cur[d], 1);
        ssrc[p] = src[i];
    } else {
        int i = (b - E_EDGES / 256) * 256 + threadIdx.x;
        int e = bid[i];
        int p = boffs[e] + atomicAdd(&bcur[e], 1);
        nlist[p] = i;
    }
}

// ================= attention logits + softmax =================
__global__ __launch_bounds__(128, 4) void att_kernel(
    const float* __restrict__ node_proj_s, const float* __restrict__ img_proj,
    const int* __restrict__ batch_ids, const float* __restrict__ Wa,
    float* __restrict__ att)
{
    __shared__ float red[2][R_REG][68];
    const int wv = threadIdx.x >> 6;
    const int n = blockIdx.x * 2 + wv;
    const int lane = threadIdx.x & 63;
    const int b = batch_ids[n];

    const float4 nps = *(const float4*)(node_proj_s + (size_t)n * P_DIM + 4 * lane);
    const float4 wa = *(const float4*)(Wa + 4 * lane);
    const float* ip0 = img_proj + (size_t)b * R_REG * P_DIM + 4 * lane;

#pragma unroll
    for (int r = 0; r < R_REG; ++r) {
        float4 ip = *(const float4*)(ip0 + (size_t)r * P_DIM);
        float t0 = fexp2(fmaf(ip.x, TANH_C, nps.x));
        float t1 = fexp2(fmaf(ip.y, TANH_C, nps.y));
        float t2 = fexp2(fmaf(ip.z, TANH_C, nps.z));
        float t3 = fexp2(fmaf(ip.w, TANH_C, nps.w));
        float p;
        p = wa.x * frcp(t0 + 1.f);
        p = fmaf(wa.y, frcp(t1 + 1.f), p);
        p = fmaf(wa.z, frcp(t2 + 1.f), p);
        p = fmaf(wa.w, frcp(t3 + 1.f), p);
        red[wv][r][lane] = p;
    }
    __syncthreads();

    float logit = -INFINITY;
    if (lane < R_REG) {
        const float* row = &red[wv][lane][0];
        float4 s4 = *(const float4*)row;
#pragma unroll
        for (int c = 4; c < 64; c += 4) {
            float4 v = *(const float4*)(row + c);
            s4.x += v.x; s4.y += v.y; s4.z += v.z; s4.w += v.w;
        }
        logit = -2.f * ((s4.x + s4.y) + (s4.z + s4.w));
    }
    float m = logit;
#pragma unroll
    for (int off = 32; off; off >>= 1) m = fmaxf(m, __shfl_xor(m, off));
    float e = (lane < R_REG) ? __expf(logit - m) : 0.f;
    float s = e;
#pragma unroll
    for (int off = 32; off; off >>= 1) s += __shfl_xor(s, off);
    if (lane < R_REG) att[(size_t)n * R_REG + lane] = e / s;
}

// ================= batched attended image feature -> A2 img cols =================
#define IA_SLICES 8
__global__ __launch_bounds__(256) void img_att_batched(
    const float* __restrict__ att, const float* __restrict__ img_feats,
    const int* __restrict__ boffs, const int* __restrict__ nlist,
    ushort* __restrict__ A2)
{
    const int b     = blockIdx.x & 63;
    const int chunk = (blockIdx.x >> 6) & 1;
    const int slice = blockIdx.x >> 7;
    const int t = threadIdx.x;
    const int c0 = chunk * 512 + 2 * t;

    const int ns = boffs[b], ne = boffs[b + 1];
    const int cnt = ne - ns;
    const int per = (cnt + IA_SLICES - 1) / IA_SLICES;
    const int i0 = ns + slice * per;
    const int i1 = min(i0 + per, ne);
    if (i0 >= i1) return;

    float2 col[R_REG];
    const float* base = img_feats + (size_t)b * R_REG * D_IMG + c0;
#pragma unroll
    for (int r = 0; r < R_REG; ++r)
        col[r] = *(const float2*)(base + (size_t)r * D_IMG);

    __shared__ float att_s[8][R_REG];
    for (int i = i0; i < i1; i += 8) {
        int g = min(8, i1 - i);
        __syncthreads();
        for (int idx = t; idx < g * R_REG; idx += 256) {
            int j = idx / R_REG, r = idx - j * R_REG;
            att_s[j][r] = att[(size_t)nlist[i + j] * R_REG + r];
        }
        __syncthreads();
        for (int j = 0; j < g; ++j) {
            float4 av[9];
#pragma unroll
            for (int q = 0; q < 9; ++q) av[q] = *(const float4*)&att_s[j][q * 4];
            float ax = 0.f, ay = 0.f;
#pragma unroll
            for (int r = 0; r < R_REG; ++r) {
                float a = (r & 2) ? ((r & 1) ? av[r >> 2].w : av[r >> 2].z)
                                  : ((r & 1) ? av[r >> 2].y : av[r >> 2].x);
                ax += a * col[r].x;
                ay += a * col[r].y;
            }
            ushort2 o; o.x = f2bf(ax); o.y = f2bf(ay);
            *(ushort2*)&A2[(size_t)nlist[i + j] * A2_LD + IMG_OFF + c0] = o;
        }
    }
}

// ================= CSR gather: wave per node, lane = 8 cols (uint4), unroll x2 ====
__device__ __forceinline__ void acc8(float* a, uint4 v) {
    a[0] += bf2f((ushort)(v.x & 0xffffu)); a[1] += bf2f((ushort)(v.x >> 16));
    a[2] += bf2f((ushort)(v.y & 0xffffu)); a[3] += bf2f((ushort)(v.y >> 16));
    a[4] += bf2f((ushort)(v.z & 0xffffu)); a[5] += bf2f((ushort)(v.z >> 16));
    a[6] += bf2f((ushort)(v.w & 0xffffu)); a[7] += bf2f((ushort)(v.w >> 16));
}

__global__ __launch_bounds__(256) void gather_neigh(
    const int* __restrict__ off, const int* __restrict__ ssrc,
    const ushort* __restrict__ A2h1 /* A2 + H1_OFF */,
    ushort* __restrict__ A2nb /* A2 + NEIGH_OFF */)
{
    const int wv = threadIdx.x >> 6;
    const int n = blockIdx.x * 4 + wv;
    const int lane = threadIdx.x & 63;
    const int e0 = off[n], e1 = off[n + 1];

    float a[8] = {};
    int e = e0;
    for (; e + 2 <= e1; e += 2) {
        int s0 = ssrc[e], s1 = ssrc[e + 1];
        uint4 v0 = *(const uint4*)(A2h1 + (size_t)s0 * A2_LD + lane * 8);
        uint4 v1 = *(const uint4*)(A2h1 + (size_t)s1 * A2_LD + lane * 8);
        acc8(a, v0);
        acc8(a, v1);
    }
    if (e < e1) {
        int s0 = ssrc[e];
        uint4 v0 = *(const uint4*)(A2h1 + (size_t)s0 * A2_LD + lane * 8);
        acc8(a, v0);
    }
    ushort8v o;
#pragma unroll
    for (int i = 0; i < 8; ++i) o[i] = f2bf(a[i]);
    *(ushort8v*)(A2nb + (size_t)n * A2_LD + lane * 8) = o;
}

extern "C" void kernel_launch(void* const* d_in, const int* in_sizes, int n_in,
                              void* d_out, int out_size, void* d_ws, size_t ws_size,
                              hipStream_t stream) {
    const float* h         = (const float*)d_in[0];
    const float* img_feats = (const float*)d_in[1];
    const int*   batch_ids = (const int*)d_in[2];
    const int*   src       = (const int*)d_in[3];
    const int*   dst       = (const int*)d_in[4];
    const float* Wf  = (const float*)d_in[5];
    const float* bf  = (const float*)d_in[6];
    const float* Wi  = (const float*)d_in[7];
    const float* bi  = (const float*)d_in[8];
    const float* Wa  = (const float*)d_in[9];
    // d_in[10] = ba: constant logit shift, cancels in softmax
    const float* Wn  = (const float*)d_in[11];
    const float* bn  = (const float*)d_in[12];
    const float* Wim = (const float*)d_in[13];
    const float* bim = (const float*)d_in[14];
    const float* Wap = (const float*)d_in[15];
    const float* bap = (const float*)d_in[16];
    float* out = (float*)d_out;
    float* ws  = (float*)d_ws;

    // ---- workspace layout (offsets in 4-byte units) ----
    ushort* h_bf    = (ushort*)(ws + 0);          // [12288][512] bf16
    ushort* A2      = (ushort*)(ws + 3145728);    // [12288][2048] bf16: img|neigh|h1
    float*  node_proj = ws + 15728640;            // [12288][256] f32 (pre-scaled)
    float*  img_proj  = ws + 18874368;            // [2304][256]  f32
    ushort* imgf_bf   = (ushort*)(ws + 19464192); // [2304][1024] bf16
    float*  att       = ws + 20643840;            // [12288][36]  f32
    ushort* WfnT  = (ushort*)(ws + 21086208);     // [768][512]
    ushort* WiT   = (ushort*)(ws + 21282816);     // [256][1024]
    ushort* Wim_bf= (ushort*)(ws + 21413888);     // [1024][512] bf16
    ushort* Wap1T = (ushort*)(ws + 21676032);     // [512][512]
    ushort* BT2   = (ushort*)(ws + 21807104);     // [512][2048]: W'^T | Wap1^T | Wap2^T
    float*  bprime = ws + 22331392;               // [512]
    // zeroed region (contiguous, one memset): deg, cur, bcnt, bcur
    int* deg  = (int*)(ws + 22331904);            // [12288]
    int* cur  = deg + N_NODES;                    // [12288]
    int* bcnt = cur + N_NODES;                    // [64]
    int* bcur = bcnt + B_EX;                      // [64]
    int* offs = bcur + B_EX;                      // [12289]
    int* boffs = offs + N_NODES + 1;              // [65]
    int* ssrc = boffs + B_EX + 1;                 // [196608]
    int* nlist = ssrc + E_EDGES;                  // [12288]

    dim3 blk(256);

    // ---- fused converts + batched transposes ----
    cvt_all<<<dim3(CVT_N3 / 256), blk, 0, stream>>>(h, img_feats, Wim, h_bf, imgf_bf, Wim_bf);
    transpose_all<<<dim3(352), blk, 0, stream>>>(Wf, Wn, Wi, Wap, WfnT, WiT, Wap1T, BT2);

    // ---- CSR build + batch sort (fused) ----
    hipMemsetAsync(deg, 0, (2 * N_NODES + 2 * B_EX) * sizeof(int), stream);
    count_all<<<dim3(E_EDGES / 256 + N_NODES / 256), blk, 0, stream>>>(dst, batch_ids, deg, bcnt);
    scan_all<<<dim3(4), blk, 0, stream>>>(deg, offs, bcnt, boffs, bim, Wap, bap, bprime);
    scatter_all<<<dim3(E_EDGES / 256 + N_NODES / 256), blk, 0, stream>>>(
        src, dst, offs, cur, ssrc, batch_ids, boffs, bcur, nlist);

    // ---- W'^T = Wap1^T @ Wim^T -> BT2 cols 0..1023 ----
    gemm_bf16mfma<false, false, false, false, true><<<dim3(D_IMG / 128, DD_OUT / 128), blk, 0, stream>>>(
        Wap1T, Wim_bf, nullptr, nullptr, nullptr, BT2, DD_OUT, D_IMG, DD_OUT, A2_LD, 0);

    // ---- fused: node_proj_s (scaled) + h1 -> A2 h1 cols ----
    gemm_fused_first<<<dim3((P_DIM + DD_OUT) / 128, N_NODES / 128), blk, 0, stream>>>(
        h_bf, WfnT, bf, bn, node_proj, A2);
    // ---- img_proj = img_feats @ Wi + bi ----
    gemm_bf16mfma<true, false, false, true, false><<<dim3(P_DIM / 128, (B_EX * R_REG) / 128), blk, 0, stream>>>(
        imgf_bf, WiT, bi, nullptr, img_proj, nullptr, B_EX * R_REG, P_DIM, D_IMG, 0, 0);
    // ---- attention ----
    att_kernel<<<dim3(N_NODES / 2), dim3(128), 0, stream>>>(node_proj, img_proj, batch_ids, Wa, att);
    img_att_batched<<<dim3(B_EX * 2 * IA_SLICES), blk, 0, stream>>>(att, img_feats, boffs, nlist, A2);
    // ---- neigh = segment_sum(h1[src], dst) -> A2 neigh cols ----
    gather_neigh<<<dim3(N_NODES / 4), blk, 0, stream>>>(offs, ssrc, A2 + H1_OFF, A2 + NEIGH_OFF);
    // ---- out = relu(A2 @ [W'; Wap1; Wap2] + b') ----
    gemm_out<<<dim3(8, 96), blk, 0, stream>>>(A2, BT2, bprime, out);
}

// Round 8
// 253.214 us; speedup vs baseline: 1.2011x; 1.0039x over previous
//
#include <hip/hip_runtime.h>
#include <cstdint>
#include <cstddef>

#define N_NODES 12288
#define B_EX    64
#define R_REG   36
#define E_EDGES 196608
#define DD_IN   512
#define DD_OUT  512
#define P_DIM   256
#define D_IMG   1024
#define TANH_C  2.885390081777927f   // 2*log2(e)

// A2 concatenated GEMM operand: [12288][2048] bf16
#define A2_LD     2048
#define IMG_OFF   0
#define NEIGH_OFF 1024
#define H1_OFF    1536

typedef unsigned short ushort;
typedef __bf16 bf16x8 __attribute__((ext_vector_type(8)));
typedef float f32x4 __attribute__((ext_vector_type(4)));
typedef ushort ushort4v __attribute__((ext_vector_type(4)));
typedef ushort ushort8v __attribute__((ext_vector_type(8)));

__device__ __forceinline__ ushort f2bf(float f) {
    uint32_t u = __float_as_uint(f);
    uint32_t r = (u + 0x7fffu + ((u >> 16) & 1u)) >> 16;
    return (ushort)r;
}
__device__ __forceinline__ float bf2f(ushort u) {
    return __uint_as_float(((uint32_t)u) << 16);
}
__device__ __forceinline__ void gload_lds16(const void* g, void* l) {
    __builtin_amdgcn_global_load_lds((const __attribute__((address_space(1))) void*)g,
                                     (__attribute__((address_space(3))) void*)l, 16, 0, 0);
}
__device__ __forceinline__ float fexp2(float x) {
    float r; asm("v_exp_f32 %0, %1" : "=v"(r) : "v"(x)); return r;
}
__device__ __forceinline__ float frcp(float x) {
    float r; asm("v_rcp_f32 %0, %1" : "=v"(r) : "v"(x)); return r;
}
// bijective XCD swizzle for nwg % 8 == 0 (identity otherwise)
__device__ __forceinline__ int xcd_swz(int lin, int nwg) {
    if ((nwg & 7) == 0) return (lin & 7) * (nwg >> 3) + (lin >> 3);
    return lin;
}

// ================= bf16 MFMA GEMM: C = [Cadd +] A @ BT^T + bias =================
template<bool HAS_BIAS, bool ADD_C, bool RELU, bool OUT_F32, bool OUT_BF16>
__global__ __launch_bounds__(256) void gemm_bf16mfma(
    const ushort* __restrict__ A, const ushort* __restrict__ BT,
    const float* __restrict__ bias, const float* __restrict__ Cadd,
    float* __restrict__ Cf, ushort* __restrict__ Cb,
    int M, int Nn, int K, int ldb, int coloff)
{
    __shared__ ushort As[128 * 64];
    __shared__ ushort Bs[128 * 64];
    const int tid = threadIdx.x;
    const int lane = tid & 63;
    const int wid = tid >> 6;
    const int wm = wid >> 1, wn = wid & 1;
    const int nx = gridDim.x;
    const int lin = xcd_swz(blockIdx.y * nx + blockIdx.x, nx * gridDim.y);
    const int m0 = (lin / nx) * 128, n0 = (lin % nx) * 128;

    f32x4 acc[4][4] = {};

    const int srow = tid >> 3;
    const int schk = tid & 7;
    const char* AsB = (const char*)As;
    const char* BsB = (const char*)Bs;

    for (int k0 = 0; k0 < K; k0 += 64) {
#pragma unroll
        for (int i = 0; i < 4; ++i) {
            int row = i * 32 + srow;
            int ca = (schk ^ (row & 7)) * 8;
            gload_lds16(A + (size_t)(m0 + row) * K + k0 + ca,
                        (char*)As + i * 4096 + wid * 1024);
            gload_lds16(BT + (size_t)(n0 + row) * K + k0 + ca,
                        (char*)Bs + i * 4096 + wid * 1024);
        }
        __syncthreads();
#pragma unroll
        for (int kk = 0; kk < 2; ++kk) {
            const int kc = kk * 4 + (lane >> 4);
            bf16x8 af[4], bfr[4];
#pragma unroll
            for (int i = 0; i < 4; ++i) {
                int row = wm * 64 + i * 16 + (lane & 15);
                af[i] = *(const bf16x8*)(AsB + row * 128 + ((kc ^ (row & 7)) << 4));
            }
#pragma unroll
            for (int j = 0; j < 4; ++j) {
                int col = wn * 64 + j * 16 + (lane & 15);
                bfr[j] = *(const bf16x8*)(BsB + col * 128 + ((kc ^ (col & 7)) << 4));
            }
#pragma unroll
            for (int i = 0; i < 4; ++i)
#pragma unroll
                for (int j = 0; j < 4; ++j)
                    acc[i][j] = __builtin_amdgcn_mfma_f32_16x16x32_bf16(af[i], bfr[j], acc[i][j], 0, 0, 0);
        }
        __syncthreads();
    }

#pragma unroll
    for (int i = 0; i < 4; ++i) {
#pragma unroll
        for (int j = 0; j < 4; ++j) {
#pragma unroll
            for (int q = 0; q < 4; ++q) {
                int row = m0 + wm * 64 + i * 16 + (lane >> 4) * 4 + q;
                int col = n0 + wn * 64 + j * 16 + (lane & 15);
                float v = acc[i][j][q];
                if (HAS_BIAS) v += bias[col];
                if (ADD_C)    v += Cadd[(size_t)row * Nn + col];
                if (RELU)     v = fmaxf(v, 0.f);
                if (OUT_F32)  Cf[(size_t)row * Nn + col] = v;
                if (OUT_BF16) Cb[(size_t)row * ldb + col + coloff] = f2bf(v);
            }
        }
    }
}

// ========== specialized final GEMM: out = relu(A2 @ BT2^T + b'), BM=128 BN=64 ==========
// grid (8, 96) = 768 blocks = exactly 3/CU. K = 2048.
__global__ __launch_bounds__(256) void gemm_out(
    const ushort* __restrict__ A, const ushort* __restrict__ BT,
    const float* __restrict__ bias, float* __restrict__ Cf)
{
    __shared__ ushort As[128 * 64];
    __shared__ ushort Bs[64 * 64];
    const int K = A2_LD;
    const int tid = threadIdx.x;
    const int lane = tid & 63;
    const int wid = tid >> 6;
    const int lin = xcd_swz(blockIdx.y * 8 + blockIdx.x, 768);
    const int m0 = (lin >> 3) * 128, n0 = (lin & 7) * 64;

    f32x4 acc[2][4] = {};

    const int srow = tid >> 3;
    const int schk = tid & 7;
    const char* AsB = (const char*)As;
    const char* BsB = (const char*)Bs;

    for (int k0 = 0; k0 < K; k0 += 64) {
#pragma unroll
        for (int i = 0; i < 4; ++i) {
            int row = i * 32 + srow;
            int ca = (schk ^ (row & 7)) * 8;
            gload_lds16(A + (size_t)(m0 + row) * K + k0 + ca,
                        (char*)As + i * 4096 + wid * 1024);
        }
#pragma unroll
        for (int i = 0; i < 2; ++i) {
            int row = i * 32 + srow;
            int cb = (schk ^ (row & 7)) * 8;
            gload_lds16(BT + (size_t)(n0 + row) * K + k0 + cb,
                        (char*)Bs + i * 4096 + wid * 1024);
        }
        __syncthreads();
#pragma unroll
        for (int kk = 0; kk < 2; ++kk) {
            const int kc = kk * 4 + (lane >> 4);
            bf16x8 af[2], bfr[4];
#pragma unroll
            for (int i = 0; i < 2; ++i) {
                int row = wid * 32 + i * 16 + (lane & 15);
                af[i] = *(const bf16x8*)(AsB + row * 128 + ((kc ^ (row & 7)) << 4));
            }
#pragma unroll
            for (int j = 0; j < 4; ++j) {
                int col = j * 16 + (lane & 15);
                bfr[j] = *(const bf16x8*)(BsB + col * 128 + ((kc ^ (col & 7)) << 4));
            }
#pragma unroll
            for (int i = 0; i < 2; ++i)
#pragma unroll
                for (int j = 0; j < 4; ++j)
                    acc[i][j] = __builtin_amdgcn_mfma_f32_16x16x32_bf16(af[i], bfr[j], acc[i][j], 0, 0, 0);
        }
        __syncthreads();
    }

#pragma unroll
    for (int i = 0; i < 2; ++i) {
#pragma unroll
        for (int j = 0; j < 4; ++j) {
#pragma unroll
            for (int q = 0; q < 4; ++q) {
                int row = m0 + wid * 32 + i * 16 + (lane >> 4) * 4 + q;
                int col = n0 + j * 16 + (lane & 15);
                float v = fmaxf(acc[i][j][q] + bias[col], 0.f);
                Cf[(size_t)row * DD_OUT + col] = v;
            }
        }
    }
}

// ========== fused first GEMM: A=h_bf [12288][512], BT=[WfT;WnT] [768][512] ==========
__global__ __launch_bounds__(256) void gemm_fused_first(
    const ushort* __restrict__ A, const ushort* __restrict__ BT,
    const float* __restrict__ biasF, const float* __restrict__ biasN,
    float* __restrict__ node_proj_s, ushort* __restrict__ A2)
{
    __shared__ ushort As[128 * 64];
    __shared__ ushort Bs[128 * 64];
    const int K = DD_IN;
    const int tid = threadIdx.x;
    const int lane = tid & 63;
    const int wid = tid >> 6;
    const int wm = wid >> 1, wn = wid & 1;
    const int nx = gridDim.x;
    const int lin = xcd_swz(blockIdx.y * nx + blockIdx.x, nx * gridDim.y);
    const int m0 = (lin / nx) * 128, n0 = (lin % nx) * 128;

    f32x4 acc[4][4] = {};

    const int srow = tid >> 3;
    const int schk = tid & 7;
    const char* AsB = (const char*)As;
    const char* BsB = (const char*)Bs;

    for (int k0 = 0; k0 < K; k0 += 64) {
#pragma unroll
        for (int i = 0; i < 4; ++i) {
            int row = i * 32 + srow;
            int ca = (schk ^ (row & 7)) * 8;
            gload_lds16(A + (size_t)(m0 + row) * K + k0 + ca,
                        (char*)As + i * 4096 + wid * 1024);
            gload_lds16(BT + (size_t)(n0 + row) * K + k0 + ca,
                        (char*)Bs + i * 4096 + wid * 1024);
        }
        __syncthreads();
#pragma unroll
        for (int kk = 0; kk < 2; ++kk) {
            const int kc = kk * 4 + (lane >> 4);
            bf16x8 af[4], bfr[4];
#pragma unroll
            for (int i = 0; i < 4; ++i) {
                int row = wm * 64 + i * 16 + (lane & 15);
                af[i] = *(const bf16x8*)(AsB + row * 128 + ((kc ^ (row & 7)) << 4));
            }
#pragma unroll
            for (int j = 0; j < 4; ++j) {
                int col = wn * 64 + j * 16 + (lane & 15);
                bfr[j] = *(const bf16x8*)(BsB + col * 128 + ((kc ^ (col & 7)) << 4));
            }
#pragma unroll
            for (int i = 0; i < 4; ++i)
#pragma unroll
                for (int j = 0; j < 4; ++j)
                    acc[i][j] = __builtin_amdgcn_mfma_f32_16x16x32_bf16(af[i], bfr[j], acc[i][j], 0, 0, 0);
        }
        __syncthreads();
    }

    if (n0 < 256) {
#pragma unroll
        for (int i = 0; i < 4; ++i)
#pragma unroll
            for (int j = 0; j < 4; ++j)
#pragma unroll
                for (int q = 0; q < 4; ++q) {
                    int row = m0 + wm * 64 + i * 16 + (lane >> 4) * 4 + q;
                    int col = n0 + wn * 64 + j * 16 + (lane & 15);
                    node_proj_s[(size_t)row * P_DIM + col] = (acc[i][j][q] + biasF[col]) * TANH_C;
                }
    } else {
#pragma unroll
        for (int i = 0; i < 4; ++i)
#pragma unroll
            for (int j = 0; j < 4; ++j)
#pragma unroll
                for (int q = 0; q < 4; ++q) {
                    int row = m0 + wm * 64 + i * 16 + (lane >> 4) * 4 + q;
                    int col = n0 - 256 + wn * 64 + j * 16 + (lane & 15);
                    A2[(size_t)row * A2_LD + H1_OFF + col] = f2bf(acc[i][j][q] + biasN[col]);
                }
    }
}

// ================= fused fp32 -> bf16 converts (h, img_feats, Wim) =================
#define CVT_N1 (N_NODES * DD_IN / 4)
#define CVT_N2 (CVT_N1 + B_EX * R_REG * D_IMG / 4)
#define CVT_N3 (CVT_N2 + D_IMG * DD_OUT / 4)
__global__ __launch_bounds__(256) void cvt_all(
    const float* __restrict__ h, const float* __restrict__ imgf,
    const float* __restrict__ Wim,
    ushort* __restrict__ h_bf, ushort* __restrict__ imgf_bf, ushort* __restrict__ Wim_bf)
{
    int i = blockIdx.x * 256 + threadIdx.x;
    const float4* src; ushort4v* dst; int j;
    if (i < CVT_N1)      { src = (const float4*)h;    dst = (ushort4v*)h_bf;    j = i; }
    else if (i < CVT_N2) { src = (const float4*)imgf; dst = (ushort4v*)imgf_bf; j = i - CVT_N1; }
    else                 { src = (const float4*)Wim;  dst = (ushort4v*)Wim_bf;  j = i - CVT_N2; }
    float4 v = src[j];
    ushort4v o;
    o[0] = f2bf(v.x); o[1] = f2bf(v.y); o[2] = f2bf(v.z); o[3] = f2bf(v.w);
    dst[j] = o;
}

// ================= batched weight transposes (all 6 in one launch) =================
__global__ __launch_bounds__(256) void transpose_all(
    const float* __restrict__ Wf, const float* __restrict__ Wn,
    const float* __restrict__ Wi, const float* __restrict__ Wap,
    ushort* __restrict__ WfnT, ushort* __restrict__ WiT,
    ushort* __restrict__ Wap1T, ushort* __restrict__ BT2)
{
    int t = blockIdx.x;
    const float* W; ushort* WT; int N, ldt, gx;
    if (t < 32)       { W = Wf;  WT = WfnT;                        N = 256; ldt = 512;  gx = 4; }
    else if (t < 96)  { W = Wn;  WT = WfnT + 256 * 512;            N = 512; ldt = 512;  gx = 8; t -= 32; }
    else if (t < 160) { W = Wi;  WT = WiT;                         N = 256; ldt = 1024; gx = 4; t -= 96; }
    else if (t < 224) { W = Wap; WT = Wap1T;                       N = 512; ldt = 512;  gx = 8; t -= 160; }
    else if (t < 288) { W = Wap; WT = BT2 + NEIGH_OFF;             N = 512; ldt = 2048; gx = 8; t -= 224; }
    else              { W = Wap + 512 * 512; WT = BT2 + H1_OFF;    N = 512; ldt = 2048; gx = 8; t -= 288; }
    const int n0 = (t % gx) * 64, k0 = (t / gx) * 64;

    __shared__ float tt[64][65];
    const int tx = threadIdx.x & 15, ty = threadIdx.x >> 4;
#pragma unroll
    for (int r = 0; r < 4; ++r) {
        float4 v = *(const float4*)&W[(size_t)(k0 + ty * 4 + r) * N + n0 + tx * 4];
        tt[ty * 4 + r][tx * 4 + 0] = v.x;
        tt[ty * 4 + r][tx * 4 + 1] = v.y;
        tt[ty * 4 + r][tx * 4 + 2] = v.z;
        tt[ty * 4 + r][tx * 4 + 3] = v.w;
    }
    __syncthreads();
    const int nl = threadIdx.x >> 2, kq = (threadIdx.x & 3) * 16;
    ushort u[16] __attribute__((aligned(16)));
#pragma unroll
    for (int c = 0; c < 16; ++c) u[c] = f2bf(tt[kq + c][nl]);
    ushort* d = &WT[(size_t)(n0 + nl) * ldt + k0 + kq];
    *(ushort8v*)d = *(ushort8v*)&u[0];
    *(ushort8v*)(d + 8) = *(ushort8v*)&u[8];
}

// ================= zero the atomic counters (replaces 40us rocclr fill) =================
#define ZERO_INTS (2 * N_NODES + 2 * B_EX)   // deg, cur, bcnt, bcur = 24704 ints
__global__ __launch_bounds__(256) void zero_counts(int* __restrict__ p) {
    int i = blockIdx.x * 256 + threadIdx.x;
    if (i < ZERO_INTS) p[i] = 0;
}

// ================= fused counting (edges by dst + nodes by batch) =================
__global__ __launch_bounds__(256) void count_all(
    const int* __restrict__ dst, const int* __restrict__ bid,
    int* __restrict__ deg, int* __restrict__ bcnt)
{
    int b = blockIdx.x;
    if (b < E_EDGES / 256) {
        atomicAdd(&deg[dst[b * 256 + threadIdx.x]], 1);
    } else {
        atomicAdd(&bcnt[bid[(b - E_EDGES / 256) * 256 + threadIdx.x]], 1);
    }
}

// ================= fused scans + bprime =================
__global__ __launch_bounds__(256) void scan_all(
    const int* __restrict__ deg, int* __restrict__ offs,
    const int* __restrict__ bcnt, int* __restrict__ boffs,
    const float* __restrict__ bim, const float* __restrict__ Wap,
    const float* __restrict__ bap, float* __restrict__ bp)
{
    const int t = threadIdx.x;
    if (blockIdx.x == 0) {
        __shared__ int s[257];
        const int base = t * 48;
        int sum = 0;
        for (int j = 0; j < 48; ++j) sum += deg[base + j];
        s[t] = sum;
        __syncthreads();
        if (t == 0) {
            int acc = 0;
            for (int i = 0; i < 256; ++i) { int v = s[i]; s[i] = acc; acc += v; }
            s[256] = acc;
        }
        __syncthreads();
        int run = s[t];
        for (int j = 0; j < 48; ++j) { offs[base + j] = run; run += deg[base + j]; }
        if (t == 255) offs[N_NODES] = s[256];
    } else if (blockIdx.x == 1) {
        if (t == 0) {
            int acc = 0;
            for (int i = 0; i < B_EX; ++i) { boffs[i] = acc; acc += bcnt[i]; }
            boffs[B_EX] = acc;
        }
    } else {
        int n = (blockIdx.x - 2) * 256 + t;
        float s = bap[n];
        for (int k = 0; k < DD_OUT; ++k) s += bim[k] * Wap[(size_t)k * DD_OUT + n];
        bp[n] = s;
    }
}

// ================= fused scatter (edges + nodes) =================
__global__ __launch_bounds__(256) void scatter_all(
    const int* __restrict__ src, const int* __restrict__ dst,
    const int* __restrict__ offs, int* __restrict__ cur, int* __restrict__ ssrc,
    const int* __restrict__ bid, const int* __restrict__ boffs,
    int* __restrict__ bcur, int* __restrict__ nlist)
{
    int b = blockIdx.x;
    if (b < E_EDGES / 256) {
        int i = b * 256 + threadIdx.x;
        int d = dst[i];
        int p = offs[d] + atomicAdd(&cur[d], 1);
        ssrc[p] = src[i];
    } else {
        int i = (b - E_EDGES / 256) * 256 + threadIdx.x;
        int e = bid[i];
        int p = boffs[e] + atomicAdd(&bcur[e], 1);
        nlist[p] = i;
    }
}

// ================= attention logits + softmax =================
__global__ __launch_bounds__(128, 4) void att_kernel(
    const float* __restrict__ node_proj_s, const float* __restrict__ img_proj,
    const int* __restrict__ batch_ids, const float* __restrict__ Wa,
    float* __restrict__ att)
{
    __shared__ float red[2][R_REG][68];
    const int wv = threadIdx.x >> 6;
    const int n = blockIdx.x * 2 + wv;
    const int lane = threadIdx.x & 63;
    const int b = batch_ids[n];

    const float4 nps = *(const float4*)(node_proj_s + (size_t)n * P_DIM + 4 * lane);
    const float4 wa = *(const float4*)(Wa + 4 * lane);
    const float* ip0 = img_proj + (size_t)b * R_REG * P_DIM + 4 * lane;

#pragma unroll
    for (int r = 0; r < R_REG; ++r) {
        float4 ip = *(const float4*)(ip0 + (size_t)r * P_DIM);
        float t0 = fexp2(fmaf(ip.x, TANH_C, nps.x));
        float t1 = fexp2(fmaf(ip.y, TANH_C, nps.y));
        float t2 = fexp2(fmaf(ip.z, TANH_C, nps.z));
        float t3 = fexp2(fmaf(ip.w, TANH_C, nps.w));
        float p;
        p = wa.x * frcp(t0 + 1.f);
        p = fmaf(wa.y, frcp(t1 + 1.f), p);
        p = fmaf(wa.z, frcp(t2 + 1.f), p);
        p = fmaf(wa.w, frcp(t3 + 1.f), p);
        red[wv][r][lane] = p;
    }
    __syncthreads();

    float logit = -INFINITY;
    if (lane < R_REG) {
        const float* row = &red[wv][lane][0];
        float4 s4 = *(const float4*)row;
#pragma unroll
        for (int c = 4; c < 64; c += 4) {
            float4 v = *(const float4*)(row + c);
            s4.x += v.x; s4.y += v.y; s4.z += v.z; s4.w += v.w;
        }
        logit = -2.f * ((s4.x + s4.y) + (s4.z + s4.w));
    }
    float m = logit;
#pragma unroll
    for (int off = 32; off; off >>= 1) m = fmaxf(m, __shfl_xor(m, off));
    float e = (lane < R_REG) ? __expf(logit - m) : 0.f;
    float s = e;
#pragma unroll
    for (int off = 32; off; off >>= 1) s += __shfl_xor(s, off);
    if (lane < R_REG) att[(size_t)n * R_REG + lane] = e / s;
}

// ================= batched attended image feature -> A2 img cols =================
#define IA_SLICES 8
__global__ __launch_bounds__(256) void img_att_batched(
    const float* __restrict__ att, const float* __restrict__ img_feats,
    const int* __restrict__ boffs, const int* __restrict__ nlist,
    ushort* __restrict__ A2)
{
    const int b     = blockIdx.x & 63;
    const int chunk = (blockIdx.x >> 6) & 1;
    const int slice = blockIdx.x >> 7;
    const int t = threadIdx.x;
    const int c0 = chunk * 512 + 2 * t;

    const int ns = boffs[b], ne = boffs[b + 1];
    const int cnt = ne - ns;
    const int per = (cnt + IA_SLICES - 1) / IA_SLICES;
    const int i0 = ns + slice * per;
    const int i1 = min(i0 + per, ne);
    if (i0 >= i1) return;

    float2 col[R_REG];
    const float* base = img_feats + (size_t)b * R_REG * D_IMG + c0;
#pragma unroll
    for (int r = 0; r < R_REG; ++r)
        col[r] = *(const float2*)(base + (size_t)r * D_IMG);

    __shared__ float att_s[8][R_REG];
    for (int i = i0; i < i1; i += 8) {
        int g = min(8, i1 - i);
        __syncthreads();
        for (int idx = t; idx < g * R_REG; idx += 256) {
            int j = idx / R_REG, r = idx - j * R_REG;
            att_s[j][r] = att[(size_t)nlist[i + j] * R_REG + r];
        }
        __syncthreads();
        for (int j = 0; j < g; ++j) {
            float4 av[9];
#pragma unroll
            for (int q = 0; q < 9; ++q) av[q] = *(const float4*)&att_s[j][q * 4];
            float ax = 0.f, ay = 0.f;
#pragma unroll
            for (int r = 0; r < R_REG; ++r) {
                float a = (r & 2) ? ((r & 1) ? av[r >> 2].w : av[r >> 2].z)
                                  : ((r & 1) ? av[r >> 2].y : av[r >> 2].x);
                ax += a * col[r].x;
                ay += a * col[r].y;
            }
            ushort2 o; o.x = f2bf(ax); o.y = f2bf(ay);
            *(ushort2*)&A2[(size_t)nlist[i + j] * A2_LD + IMG_OFF + c0] = o;
        }
    }
}

// ================= CSR gather: wave per node, lane = 8 cols (uint4), unroll x2 ====
__device__ __forceinline__ void acc8(float* a, uint4 v) {
    a[0] += bf2f((ushort)(v.x & 0xffffu)); a[1] += bf2f((ushort)(v.x >> 16));
    a[2] += bf2f((ushort)(v.y & 0xffffu)); a[3] += bf2f((ushort)(v.y >> 16));
    a[4] += bf2f((ushort)(v.z & 0xffffu)); a[5] += bf2f((ushort)(v.z >> 16));
    a[6] += bf2f((ushort)(v.w & 0xffffu)); a[7] += bf2f((ushort)(v.w >> 16));
}

__global__ __launch_bounds__(256) void gather_neigh(
    const int* __restrict__ off, const int* __restrict__ ssrc,
    const ushort* __restrict__ A2h1 /* A2 + H1_OFF */,
    ushort* __restrict__ A2nb /* A2 + NEIGH_OFF */)
{
    const int wv = threadIdx.x >> 6;
    const int n = blockIdx.x * 4 + wv;
    const int lane = threadIdx.x & 63;
    const int e0 = off[n], e1 = off[n + 1];

    float a[8] = {};
    int e = e0;
    for (; e + 2 <= e1; e += 2) {
        int s0 = ssrc[e], s1 = ssrc[e + 1];
        uint4 v0 = *(const uint4*)(A2h1 + (size_t)s0 * A2_LD + lane * 8);
        uint4 v1 = *(const uint4*)(A2h1 + (size_t)s1 * A2_LD + lane * 8);
        acc8(a, v0);
        acc8(a, v1);
    }
    if (e < e1) {
        int s0 = ssrc[e];
        uint4 v0 = *(const uint4*)(A2h1 + (size_t)s0 * A2_LD + lane * 8);
        acc8(a, v0);
    }
    ushort8v o;
#pragma unroll
    for (int i = 0; i < 8; ++i) o[i] = f2bf(a[i]);
    *(ushort8v*)(A2nb + (size_t)n * A2_LD + lane * 8) = o;
}

extern "C" void kernel_launch(void* const* d_in, const int* in_sizes, int n_in,
                              void* d_out, int out_size, void* d_ws, size_t ws_size,
                              hipStream_t stream) {
    const float* h         = (const float*)d_in[0];
    const float* img_feats = (const float*)d_in[1];
    const int*   batch_ids = (const int*)d_in[2];
    const int*   src       = (const int*)d_in[3];
    const int*   dst       = (const int*)d_in[4];
    const float* Wf  = (const float*)d_in[5];
    const float* bf  = (const float*)d_in[6];
    const float* Wi  = (const float*)d_in[7];
    const float* bi  = (const float*)d_in[8];
    const float* Wa  = (const float*)d_in[9];
    // d_in[10] = ba: constant logit shift, cancels in softmax
    const float* Wn  = (const float*)d_in[11];
    const float* bn  = (const float*)d_in[12];
    const float* Wim = (const float*)d_in[13];
    const float* bim = (const float*)d_in[14];
    const float* Wap = (const float*)d_in[15];
    const float* bap = (const float*)d_in[16];
    float* out = (float*)d_out;
    float* ws  = (float*)d_ws;

    // ---- workspace layout (offsets in 4-byte units) ----
    ushort* h_bf    = (ushort*)(ws + 0);          // [12288][512] bf16
    ushort* A2      = (ushort*)(ws + 3145728);    // [12288][2048] bf16: img|neigh|h1
    float*  node_proj = ws + 15728640;            // [12288][256] f32 (pre-scaled)
    float*  img_proj  = ws + 18874368;            // [2304][256]  f32
    ushort* imgf_bf   = (ushort*)(ws + 19464192); // [2304][1024] bf16
    float*  att       = ws + 20643840;            // [12288][36]  f32
    ushort* WfnT  = (ushort*)(ws + 21086208);     // [768][512]
    ushort* WiT   = (ushort*)(ws + 21282816);     // [256][1024]
    ushort* Wim_bf= (ushort*)(ws + 21413888);     // [1024][512] bf16
    ushort* Wap1T = (ushort*)(ws + 21676032);     // [512][512]
    ushort* BT2   = (ushort*)(ws + 21807104);     // [512][2048]: W'^T | Wap1^T | Wap2^T
    float*  bprime = ws + 22331392;               // [512]
    // zeroed region (contiguous, one zero kernel): deg, cur, bcnt, bcur
    int* deg  = (int*)(ws + 22331904);            // [12288]
    int* cur  = deg + N_NODES;                    // [12288]
    int* bcnt = cur + N_NODES;                    // [64]
    int* bcur = bcnt + B_EX;                      // [64]
    int* offs = bcur + B_EX;                      // [12289]
    int* boffs = offs + N_NODES + 1;              // [65]
    int* ssrc = boffs + B_EX + 1;                 // [196608]
    int* nlist = ssrc + E_EDGES;                  // [12288]

    dim3 blk(256);

    // ---- fused converts + batched transposes ----
    cvt_all<<<dim3(CVT_N3 / 256), blk, 0, stream>>>(h, img_feats, Wim, h_bf, imgf_bf, Wim_bf);
    transpose_all<<<dim3(352), blk, 0, stream>>>(Wf, Wn, Wi, Wap, WfnT, WiT, Wap1T, BT2);

    // ---- CSR build + batch sort (fused) ----
    zero_counts<<<dim3((ZERO_INTS + 255) / 256), blk, 0, stream>>>(deg);
    count_all<<<dim3(E_EDGES / 256 + N_NODES / 256), blk, 0, stream>>>(dst, batch_ids, deg, bcnt);
    scan_all<<<dim3(4), blk, 0, stream>>>(deg, offs, bcnt, boffs, bim, Wap, bap, bprime);
    scatter_all<<<dim3(E_EDGES / 256 + N_NODES / 256), blk, 0, stream>>>(
        src, dst, offs, cur, ssrc, batch_ids, boffs, bcur, nlist);

    // ---- W'^T = Wap1^T @ Wim^T -> BT2 cols 0..1023 ----
    gemm_bf16mfma<false, false, false, false, true><<<dim3(D_IMG / 128, DD_OUT / 128), blk, 0, stream>>>(
        Wap1T, Wim_bf, nullptr, nullptr, nullptr, BT2, DD_OUT, D_IMG, DD_OUT, A2_LD, 0);

    // ---- fused: node_proj_s (scaled) + h1 -> A2 h1 cols ----
    gemm_fused_first<<<dim3((P_DIM + DD_OUT) / 128, N_NODES / 128), blk, 0, stream>>>(
        h_bf, WfnT, bf, bn, node_proj, A2);
    // ---- img_proj = img_feats @ Wi + bi ----
    gemm_bf16mfma<true, false, false, true, false><<<dim3(P_DIM / 128, (B_EX * R_REG) / 128), blk, 0, stream>>>(
        imgf_bf, WiT, bi, nullptr, img_proj, nullptr, B_EX * R_REG, P_DIM, D_IMG, 0, 0);
    // ---- attention ----
    att_kernel<<<dim3(N_NODES / 2), dim3(128), 0, stream>>>(node_proj, img_proj, batch_ids, Wa, att);
    img_att_batched<<<dim3(B_EX * 2 * IA_SLICES), blk, 0, stream>>>(att, img_feats, boffs, nlist, A2);
    // ---- neigh = segment_sum(h1[src], dst) -> A2 neigh cols ----
    gather_neigh<<<dim3(N_NODES / 4), blk, 0, stream>>>(offs, ssrc, A2 + H1_OFF, A2 + NEIGH_OFF);
    // ---- out = relu(A2 @ [W'; Wap1; Wap2] + b') ----
    gemm_out<<<dim3(8, 96), blk, 0, stream>>>(A2, BT2, bprime, out);
}